// Round 1
// 157.422 us; speedup vs baseline: 1.0080x; 1.0080x over previous
//
#include <hip/hip_runtime.h>

#define BB 4
#define TT 4096
#define CC 1024
#define HH 64
#define AW 4   // attn key-split waves per block

typedef unsigned short us;
typedef us v8u __attribute__((ext_vector_type(8)));
typedef us v4u __attribute__((ext_vector_type(4)));
typedef __bf16 v8bf __attribute__((ext_vector_type(8)));
typedef float v4f __attribute__((ext_vector_type(4)));

__device__ __forceinline__ us f2bf(float f) {
  unsigned u = __builtin_bit_cast(unsigned, f);
  u += 0x7fffu + ((u >> 16) & 1u);
  return (us)(u >> 16);
}
__device__ __forceinline__ v8bf ldb(const us* p) {
  return __builtin_bit_cast(v8bf, *(const v8u*)p);
}

// ---- convert weights fp32 -> fragment-packed bf16: wpack[t][oc][kc][lane][8] ----
__global__ __launch_bounds__(256) void convertw_kernel(const float* __restrict__ Wk,
                                                       const float* __restrict__ Wq,
                                                       const float* __restrict__ Wv,
                                                       us* __restrict__ wpack) {
  const int g = blockIdx.x * 256 + threadIdx.x;   // [0, 3*4*32*64)
  const int t = g >> 13;
  const int rem = g & 8191;
  const int oc = rem >> 11;
  const int kc = (rem >> 6) & 31;
  const int lane = rem & 63;
  const float* W = (t == 0) ? Wq : ((t == 1) ? Wk : Wv);
  const int h  = oc * 16 + (lane & 15);
  const int d0 = kc * 32 + (lane >> 4) * 8;
  const float4* src = (const float4*)(W + h * CC + d0);
  const float4 f0 = src[0], f1 = src[1];
  v8u o;
  o[0]=f2bf(f0.x); o[1]=f2bf(f0.y); o[2]=f2bf(f0.z); o[3]=f2bf(f0.w);
  o[4]=f2bf(f1.x); o[5]=f2bf(f1.y); o[6]=f2bf(f1.z); o[7]=f2bf(f1.w);
  *(v8u*)(wpack + (size_t)g * 8) = o;
}

// Packed activation layouts (bf16):
//  qpack/kpack: [b][tile32][half][dhalf][lane][8]; vpack: [b][tile32][oc][lane][8]

// ---------------- Projection v5: no x-staging, 8 waves (2 rg x 4 kq), direct global A-frags ----
// Each wave: 16 rows x 256-wide K-quarter, 8 kc iters x 12 MFMA, zero barriers in K-loop.
// Cross-wave K-reduce through 72 KB fp32 LDS partials (2 blocks/CU, 4 waves/SIMD).
__global__ __launch_bounds__(512, 4) void proj_kernel(
    const float* __restrict__ x, const us* __restrict__ wpack,
    us* __restrict__ qpack, us* __restrict__ kpack, us* __restrict__ vpack)
{
  // partials from kq=1..3: [kq-1][rg][tensor][oc][lane][4] = 73728 B
  __shared__ __align__(16) float red[3][2][3][4][64][4];

  const int tid  = threadIdx.x;
  const int lane = tid & 63, w = tid >> 6;
  const int i16 = lane & 15, quad = lane >> 4;
  const int rg = w & 1, kq = w >> 1;          // row-group (16 rows), K-quarter (256)
  const int rows0 = blockIdx.x * 32;

  // A-frag source: row = rows0 + rg*16 + i16, cols = kq*256 + kc*32 + quad*8
  // quads 0..3 of each i16 cover 128 contiguous bytes per row -> fully-used segments.
  const float* xp = x + (size_t)(rows0 + rg * 16 + i16) * CC + kq * 256 + quad * 8;

  v4f zero = {0.f, 0.f, 0.f, 0.f};
  v4f acc[3][4];
  #pragma unroll
  for (int t = 0; t < 3; t++)
    #pragma unroll
    for (int oc = 0; oc < 4; oc++) acc[t][oc] = zero;

  #pragma unroll 2
  for (int kc = 0; kc < 8; kc++) {
    const float4 f0 = *(const float4*)(xp + kc * 32);
    const float4 f1 = *(const float4*)(xp + kc * 32 + 4);
    v8u au;
    au[0]=f2bf(f0.x); au[1]=f2bf(f0.y); au[2]=f2bf(f0.z); au[3]=f2bf(f0.w);
    au[4]=f2bf(f1.x); au[5]=f2bf(f1.y); au[6]=f2bf(f1.z); au[7]=f2bf(f1.w);
    const v8bf a = __builtin_bit_cast(v8bf, au);
    const size_t wo = (size_t)(kq * 8 + kc) * 512 + lane * 8;
    #pragma unroll
    for (int oc = 0; oc < 4; oc++) {
      acc[0][oc] = __builtin_amdgcn_mfma_f32_16x16x32_bf16(a, ldb(wpack + (0*4+oc)*16384 + wo), acc[0][oc], 0, 0, 0);
      acc[1][oc] = __builtin_amdgcn_mfma_f32_16x16x32_bf16(a, ldb(wpack + (1*4+oc)*16384 + wo), acc[1][oc], 0, 0, 0);
      acc[2][oc] = __builtin_amdgcn_mfma_f32_16x16x32_bf16(a, ldb(wpack + (2*4+oc)*16384 + wo), acc[2][oc], 0, 0, 0);
    }
  }

  if (kq) {
    #pragma unroll
    for (int t = 0; t < 3; t++)
      #pragma unroll
      for (int oc = 0; oc < 4; oc++)
        *(v4f*)&red[kq - 1][rg][t][oc][lane][0] = acc[t][oc];
  }
  __syncthreads();

  if (kq == 0) {
    #pragma unroll
    for (int p = 0; p < 3; p++)
      #pragma unroll
      for (int t = 0; t < 3; t++)
        #pragma unroll
        for (int oc = 0; oc < 4; oc++) {
          const v4f pv = *(const v4f*)&red[p][rg][t][oc][lane][0];
          #pragma unroll
          for (int r = 0; r < 4; r++) acc[t][oc][r] += pv[r];
        }

    const float COEF = 0.015625f * 1.4426950408889634f;  // scale^2 * log2(e), folded into q
    const int b    = (rows0 >> 12);
    const int tile = (rows0 & (TT - 1)) >> 5;

    #pragma unroll
    for (int oc = 0; oc < 4; oc++) {
      const int h = oc * 16 + i16;
      #pragma unroll
      for (int r = 0; r < 4; r++) {
        const int tr = quad * 4 + r;
        const int lane2 = tr + 16 * ((h >> 3) & 3);
        const size_t idx = ((((size_t)(b * 128 + tile) * 2 + rg) * 2 + (h >> 5)) * 64 + lane2) * 8 + (h & 7);
        qpack[idx] = f2bf(acc[0][oc][r] * COEF);
        kpack[idx] = f2bf(acc[1][oc][r]);
      }
      const int lane3 = i16 + 16 * (rg * 2 + (quad >> 1));
      v4u pk;
      #pragma unroll
      for (int r = 0; r < 4; r++) pk[r] = f2bf(acc[2][oc][r]);
      *(v4u*)&vpack[(((size_t)(b * 128 + tile) * 4 + oc) * 64 + lane3) * 8 + (quad & 1) * 4] = pk;
    }
  }
}

// ---------------- Flash attention v4: 4-wave blocks, P double-buffer pipeline ----------------
__global__ __launch_bounds__(256) void attn_kernel(
    const us* __restrict__ qpack, const us* __restrict__ kpack,
    const us* __restrict__ vpack, float* __restrict__ out)
{
  // per-wave 2148 floats: loop uses first 1280 (P dbuf us[2][2][16][40]);
  // after loop: O^T [64][33] + lsum[32] at 2112.
  __shared__ float shbuf[AW][2148];

  const int tid  = threadIdx.x;
  const int lane = tid & 63, warp = tid >> 6;
  const int i16 = lane & 15, quad = lane >> 4;

  // pairing: blocks p and p+256 share a CU -> complementary key-range lengths
  const int p = blockIdx.x & 255, s = blockIdx.x >> 8;
  const int b  = p & 3;
  const int q0 = p >> 2;
  const int qb = s ? (127 - q0) : q0;
  const int i0 = qb << 5;
  const int nt = min(qb + 2, 128);

  us* Pw = (us*)shbuf[warp];
  const float NEGINF = -__builtin_inff();

  v8bf qf[2][2];
  #pragma unroll
  for (int ih = 0; ih < 2; ih++)
    #pragma unroll
    for (int g = 0; g < 2; g++)
      qf[ih][g] = ldb(qpack + ((((size_t)(b * 128 + qb) * 2 + ih) * 2 + g) * 64 + lane) * 8);

  v4f zero = {0.f, 0.f, 0.f, 0.f};
  v4f oacc[2][4];
  #pragma unroll
  for (int ih = 0; ih < 2; ih++)
    #pragma unroll
    for (int oc = 0; oc < 4; oc++) oacc[ih][oc] = zero;
  float lsum[2] = {0.f, 0.f};

  auto loadK = [&](int t, v8bf kf[2][2]) {
    #pragma unroll
    for (int f = 0; f < 2; f++)
      #pragma unroll
      for (int g = 0; g < 2; g++)
        kf[f][g] = ldb(kpack + ((((size_t)(b * 128 + t) * 2 + f) * 2 + g) * 64 + lane) * 8);
  };
  auto loadV = [&](int t, v8bf vf[4]) {
    #pragma unroll
    for (int oc = 0; oc < 4; oc++)
      vf[oc] = ldb(vpack + (((size_t)(b * 128 + t) * 4 + oc) * 64 + lane) * 8);
  };
  auto qk_exp_store = [&](int t, const v8bf kf[2][2], int buf) {
    v4f sacc[2][2];
    #pragma unroll
    for (int ih = 0; ih < 2; ih++)
      #pragma unroll
      for (int f = 0; f < 2; f++) {
        v4f sv = zero;
        sv = __builtin_amdgcn_mfma_f32_16x16x32_bf16(kf[f][0], qf[ih][0], sv, 0, 0, 0);
        sv = __builtin_amdgcn_mfma_f32_16x16x32_bf16(kf[f][1], qf[ih][1], sv, 0, 0, 0);
        sacc[ih][f] = sv;
      }
    const int j0 = t * 32;
    const bool needMask = (t >= qb);
    #pragma unroll
    for (int ih = 0; ih < 2; ih++) {
      float ps[8];
      #pragma unroll
      for (int f = 0; f < 2; f++)
        #pragma unroll
        for (int r = 0; r < 4; r++) {
          float sv = fminf(sacc[ih][f][r], 80.f);
          if (needMask) {
            const int j = j0 + f * 16 + quad * 4 + r;
            const int i = i0 + ih * 16 + i16;
            sv = (j <= i + 1) ? sv : NEGINF;
          }
          ps[f * 4 + r] = exp2f(sv);
          lsum[ih] += ps[f * 4 + r];
        }
      #pragma unroll
      for (int f = 0; f < 2; f++) {
        v4u pk;
        #pragma unroll
        for (int r = 0; r < 4; r++) pk[r] = f2bf(ps[f * 4 + r]);
        *(v4u*)&Pw[buf * 1280 + ih * 640 + i16 * 40 + f * 16 + quad * 4] = pk;
      }
    }
  };
  auto pv = [&](int buf, const v8bf vf[4]) {
    #pragma unroll
    for (int ih = 0; ih < 2; ih++) {
      v8bf pf = __builtin_bit_cast(v8bf, *(const v8u*)&Pw[buf * 1280 + ih * 640 + i16 * 40 + quad * 8]);
      #pragma unroll
      for (int oc = 0; oc < 4; oc++)
        oacc[ih][oc] = __builtin_amdgcn_mfma_f32_16x16x32_bf16(vf[oc], pf, oacc[ih][oc], 0, 0, 0);
    }
  };

  // software pipeline: PV(t) uses P stored one iteration earlier (lgkm long retired)
  int t = warp, buf = 0;
  if (t < nt) {
    v8bf kf[2][2], vprev[4];
    loadK(t, kf); loadV(t, vprev);
    qk_exp_store(t, kf, 0);
    for (t += AW; t < nt; t += AW) {
      v8bf kf2[2][2], vnew[4];
      loadK(t, kf2); loadV(t, vnew);
      pv(buf, vprev);                 // reads P(buf) written last iteration
      qk_exp_store(t, kf2, buf ^ 1);  // writes the other buffer
      #pragma unroll
      for (int v = 0; v < 4; v++) vprev[v] = vnew[v];
      buf ^= 1;
    }
    pv(buf, vprev);                   // drain
  }

  // publish per-wave partials
  #pragma unroll
  for (int ih = 0; ih < 2; ih++) {
    lsum[ih] += __shfl_xor(lsum[ih], 16, 64);
    lsum[ih] += __shfl_xor(lsum[ih], 32, 64);
    #pragma unroll
    for (int oc = 0; oc < 4; oc++)
      #pragma unroll
      for (int r = 0; r < 4; r++)
        shbuf[warp][(oc * 16 + quad * 4 + r) * 33 + ih * 16 + i16] = oacc[ih][oc][r];
  }
  if (lane < 16) {
    shbuf[warp][2112 + lane]      = lsum[0];
    shbuf[warp][2112 + 16 + lane] = lsum[1];
  }
  __syncthreads();

  // merge AW key-split waves; thread (iw, o) handles rows i = iw + 4*rr
  const int o  = tid & 63;
  const int iw = tid >> 6;
  #pragma unroll
  for (int rr = 0; rr < 8; rr++) {
    const int i = iw + rr * 4;
    float L = 0.f, O = 0.f;
    #pragma unroll
    for (int w = 0; w < AW; w++) {
      L += shbuf[w][2112 + i];
      O += shbuf[w][o * 33 + i];
    }
    out[(size_t)(b * TT + i0 + i) * HH + o] = O / L;
  }
}

extern "C" void kernel_launch(void* const* d_in, const int* in_sizes, int n_in,
                              void* d_out, int out_size, void* d_ws, size_t ws_size,
                              hipStream_t stream) {
  const size_t NWP = 3 * 4 * 32 * 64 * 8;      // 196,608 elems wpack
  const size_t NP  = (size_t)BB * TT * HH;     // 4,194,304 elems per pack

  us* wpack = (us*)d_ws;
  us* qpack = wpack + NWP;
  us* kpack = qpack + NP;
  us* vpack = kpack + NP;                      // total ws ~25.5 MB
  float* out = (float*)d_out;

  convertw_kernel<<<96, 256, 0, stream>>>(
      (const float*)d_in[1], (const float*)d_in[2], (const float*)d_in[3], wpack);
  proj_kernel<<<BB * TT / 32, 512, 0, stream>>>(
      (const float*)d_in[0], wpack, qpack, kpack, vpack);
  attn_kernel<<<512, 256, 0, stream>>>(qpack, kpack, vpack, out);
}

// Round 3
// 146.065 us; speedup vs baseline: 1.0863x; 1.0778x over previous
//
#include <hip/hip_runtime.h>

#define BB 4
#define TT 4096
#define CC 1024
#define HH 64
#define AW 4   // attn key-split waves per block

typedef unsigned short us;
typedef us v8u __attribute__((ext_vector_type(8)));
typedef us v4u __attribute__((ext_vector_type(4)));
typedef __bf16 v8bf __attribute__((ext_vector_type(8)));
typedef float v4f __attribute__((ext_vector_type(4)));

__device__ __forceinline__ us f2bf(float f) {
  unsigned u = __builtin_bit_cast(unsigned, f);
  u += 0x7fffu + ((u >> 16) & 1u);
  return (us)(u >> 16);
}
__device__ __forceinline__ v8bf ldb(const us* p) {
  return __builtin_bit_cast(v8bf, *(const v8u*)p);
}

// ---- convert weights fp32 -> fragment-packed bf16: wpack[t][oc][kc][lane][8] ----
__global__ __launch_bounds__(256) void convertw_kernel(const float* __restrict__ Wk,
                                                       const float* __restrict__ Wq,
                                                       const float* __restrict__ Wv,
                                                       us* __restrict__ wpack) {
  const int g = blockIdx.x * 256 + threadIdx.x;   // [0, 3*4*32*64)
  const int t = g >> 13;
  const int rem = g & 8191;
  const int oc = rem >> 11;
  const int kc = (rem >> 6) & 31;
  const int lane = rem & 63;
  const float* W = (t == 0) ? Wq : ((t == 1) ? Wk : Wv);
  const int h  = oc * 16 + (lane & 15);
  const int d0 = kc * 32 + (lane >> 4) * 8;
  const float4* src = (const float4*)(W + h * CC + d0);
  const float4 f0 = src[0], f1 = src[1];
  v8u o;
  o[0]=f2bf(f0.x); o[1]=f2bf(f0.y); o[2]=f2bf(f0.z); o[3]=f2bf(f0.w);
  o[4]=f2bf(f1.x); o[5]=f2bf(f1.y); o[6]=f2bf(f1.z); o[7]=f2bf(f1.w);
  *(v8u*)(wpack + (size_t)g * 8) = o;
}

// Packed activation layouts (bf16):
//  qpack/kpack: [b][tile32][half][dhalf][lane][8]; vpack: [b][tile32][oc][lane][8]

// ---------------- Projection v7: output-stationary waves, weights read ONCE, 2-pass K ----
// 256 blocks x 768 threads (12 waves). Block owns 64 token rows; wave owns one (tensor,oc)
// output panel with full-K in-register accumulation -> zero cross-wave reduce.
// K split in two 512-wide passes so the x LDS stage is 66,560 B (2 blocks/CU, 6 waves/SIMD).
// Weight frag loaded once per (wave,kc), reused for 4 row-groups: per-CU weight VMEM
// instrs drop 1536 -> 384 vs v5 (the round-0/1 invariant bottleneck).
__global__ __launch_bounds__(768, 6) void proj_kernel(
    const float* __restrict__ x, const us* __restrict__ wpack,
    us* __restrict__ qpack, us* __restrict__ kpack, us* __restrict__ vpack)
{
  __shared__ __align__(16) us xlds[64][520];   // 66,560 B; bank-quad (row+q+4kc)%8 uniform

  const int tid  = threadIdx.x;
  const int lane = tid & 63, w = tid >> 6;
  const int i16 = lane & 15, quad = lane >> 4;
  const int t = w >> 2, oc = w & 3;             // wave -> (tensor, oc) panel
  const int rows0 = blockIdx.x * 64;

  const us* wp = wpack + (size_t)w * 16384 + lane * 8;   // w == t*4+oc
  v4f zero = {0.f, 0.f, 0.f, 0.f};
  v4f acc[4] = {zero, zero, zero, zero};

  #pragma unroll
  for (int ph = 0; ph < 2; ph++) {
    if (ph) __syncthreads();                    // pass-0 reads done before overwrite
    // ---- stage 64 x 512 fp32 -> bf16 LDS, coalesced (128 f4 per row) ----
    const float4* xg4 = (const float4*)(x + (size_t)rows0 * CC + ph * 512);
    for (int i = tid; i < 8192; i += 768) {
      const int r = i >> 7, c = i & 127;
      const float4 f = xg4[r * 256 + c];
      v4u o; o[0]=f2bf(f.x); o[1]=f2bf(f.y); o[2]=f2bf(f.z); o[3]=f2bf(f.w);
      *(v4u*)&xlds[r][c * 4] = o;
    }
    __syncthreads();

    // ---- 16 kc x (1 weight load + 4 ds_read_b128 + 4 MFMA), zero barriers ----
    #pragma unroll 4
    for (int kc = 0; kc < 16; kc++) {
      const v8bf wf = ldb(wp + (ph * 16 + kc) * 512);
      #pragma unroll
      for (int rg = 0; rg < 4; rg++) {
        const v8bf a = ldb(&xlds[rg * 16 + i16][kc * 32 + quad * 8]);
        acc[rg] = __builtin_amdgcn_mfma_f32_16x16x32_bf16(a, wf, acc[rg], 0, 0, 0);
      }
    }
  }

  // ---- epilogue: pack stores (layouts identical to v5) ----
  const float COEF = 0.015625f * 1.4426950408889634f;  // scale^2 * log2(e), folded into q
  const int b     = rows0 >> 12;
  const int tile0 = (rows0 & (TT - 1)) >> 5;

  if (t < 2) {
    us* dst = t ? kpack : qpack;
    const float c = t ? 1.0f : COEF;
    const int h = oc * 16 + i16;
    #pragma unroll
    for (int rg16 = 0; rg16 < 4; rg16++) {
      const int tile = tile0 + (rg16 >> 1);
      const int rg = rg16 & 1;
      #pragma unroll
      for (int r = 0; r < 4; r++) {
        const int tr = quad * 4 + r;
        const int lane2 = tr + 16 * ((h >> 3) & 3);
        const size_t idx = ((((size_t)(b * 128 + tile) * 2 + rg) * 2 + (h >> 5)) * 64 + lane2) * 8 + (h & 7);
        dst[idx] = f2bf(acc[rg16][r] * c);
      }
    }
  } else {
    #pragma unroll
    for (int rg16 = 0; rg16 < 4; rg16++) {
      const int tile = tile0 + (rg16 >> 1);
      const int rg = rg16 & 1;
      const int lane3 = i16 + 16 * (rg * 2 + (quad >> 1));
      v4u pk;
      #pragma unroll
      for (int r = 0; r < 4; r++) pk[r] = f2bf(acc[rg16][r]);
      *(v4u*)&vpack[(((size_t)(b * 128 + tile) * 4 + oc) * 64 + lane3) * 8 + (quad & 1) * 4] = pk;
    }
  }
}

// ---------------- Flash attention v4: 4-wave blocks, P double-buffer pipeline ----------------
__global__ __launch_bounds__(256) void attn_kernel(
    const us* __restrict__ qpack, const us* __restrict__ kpack,
    const us* __restrict__ vpack, float* __restrict__ out)
{
  // per-wave 2148 floats: loop uses first 1280 (P dbuf us[2][2][16][40]);
  // after loop: O^T [64][33] + lsum[32] at 2112.
  __shared__ float shbuf[AW][2148];

  const int tid  = threadIdx.x;
  const int lane = tid & 63, warp = tid >> 6;
  const int i16 = lane & 15, quad = lane >> 4;

  // pairing: blocks p and p+256 share a CU -> complementary key-range lengths
  const int p = blockIdx.x & 255, s = blockIdx.x >> 8;
  const int b  = p & 3;
  const int q0 = p >> 2;
  const int qb = s ? (127 - q0) : q0;
  const int i0 = qb << 5;
  const int nt = min(qb + 2, 128);

  us* Pw = (us*)shbuf[warp];
  const float NEGINF = -__builtin_inff();

  v8bf qf[2][2];
  #pragma unroll
  for (int ih = 0; ih < 2; ih++)
    #pragma unroll
    for (int g = 0; g < 2; g++)
      qf[ih][g] = ldb(qpack + ((((size_t)(b * 128 + qb) * 2 + ih) * 2 + g) * 64 + lane) * 8);

  v4f zero = {0.f, 0.f, 0.f, 0.f};
  v4f oacc[2][4];
  #pragma unroll
  for (int ih = 0; ih < 2; ih++)
    #pragma unroll
    for (int oc = 0; oc < 4; oc++) oacc[ih][oc] = zero;
  float lsum[2] = {0.f, 0.f};

  auto loadK = [&](int t, v8bf kf[2][2]) {
    #pragma unroll
    for (int f = 0; f < 2; f++)
      #pragma unroll
      for (int g = 0; g < 2; g++)
        kf[f][g] = ldb(kpack + ((((size_t)(b * 128 + t) * 2 + f) * 2 + g) * 64 + lane) * 8);
  };
  auto loadV = [&](int t, v8bf vf[4]) {
    #pragma unroll
    for (int oc = 0; oc < 4; oc++)
      vf[oc] = ldb(vpack + (((size_t)(b * 128 + t) * 4 + oc) * 64 + lane) * 8);
  };
  auto qk_exp_store = [&](int t, const v8bf kf[2][2], int buf) {
    v4f sacc[2][2];
    #pragma unroll
    for (int ih = 0; ih < 2; ih++)
      #pragma unroll
      for (int f = 0; f < 2; f++) {
        v4f sv = zero;
        sv = __builtin_amdgcn_mfma_f32_16x16x32_bf16(kf[f][0], qf[ih][0], sv, 0, 0, 0);
        sv = __builtin_amdgcn_mfma_f32_16x16x32_bf16(kf[f][1], qf[ih][1], sv, 0, 0, 0);
        sacc[ih][f] = sv;
      }
    const int j0 = t * 32;
    const bool needMask = (t >= qb);
    #pragma unroll
    for (int ih = 0; ih < 2; ih++) {
      float ps[8];
      #pragma unroll
      for (int f = 0; f < 2; f++)
        #pragma unroll
        for (int r = 0; r < 4; r++) {
          float sv = fminf(sacc[ih][f][r], 80.f);
          if (needMask) {
            const int j = j0 + f * 16 + quad * 4 + r;
            const int i = i0 + ih * 16 + i16;
            sv = (j <= i + 1) ? sv : NEGINF;
          }
          ps[f * 4 + r] = exp2f(sv);
          lsum[ih] += ps[f * 4 + r];
        }
      #pragma unroll
      for (int f = 0; f < 2; f++) {
        v4u pk;
        #pragma unroll
        for (int r = 0; r < 4; r++) pk[r] = f2bf(ps[f * 4 + r]);
        *(v4u*)&Pw[buf * 1280 + ih * 640 + i16 * 40 + f * 16 + quad * 4] = pk;
      }
    }
  };
  auto pv = [&](int buf, const v8bf vf[4]) {
    #pragma unroll
    for (int ih = 0; ih < 2; ih++) {
      v8bf pf = __builtin_bit_cast(v8bf, *(const v8u*)&Pw[buf * 1280 + ih * 640 + i16 * 40 + quad * 8]);
      #pragma unroll
      for (int oc = 0; oc < 4; oc++)
        oacc[ih][oc] = __builtin_amdgcn_mfma_f32_16x16x32_bf16(vf[oc], pf, oacc[ih][oc], 0, 0, 0);
    }
  };

  // software pipeline: PV(t) uses P stored one iteration earlier (lgkm long retired)
  int t = warp, buf = 0;
  if (t < nt) {
    v8bf kf[2][2], vprev[4];
    loadK(t, kf); loadV(t, vprev);
    qk_exp_store(t, kf, 0);
    for (t += AW; t < nt; t += AW) {
      v8bf kf2[2][2], vnew[4];
      loadK(t, kf2); loadV(t, vnew);
      pv(buf, vprev);                 // reads P(buf) written last iteration
      qk_exp_store(t, kf2, buf ^ 1);  // writes the other buffer
      #pragma unroll
      for (int v = 0; v < 4; v++) vprev[v] = vnew[v];
      buf ^= 1;
    }
    pv(buf, vprev);                   // drain
  }

  // publish per-wave partials
  #pragma unroll
  for (int ih = 0; ih < 2; ih++) {
    lsum[ih] += __shfl_xor(lsum[ih], 16, 64);
    lsum[ih] += __shfl_xor(lsum[ih], 32, 64);
    #pragma unroll
    for (int oc = 0; oc < 4; oc++)
      #pragma unroll
      for (int r = 0; r < 4; r++)
        shbuf[warp][(oc * 16 + quad * 4 + r) * 33 + ih * 16 + i16] = oacc[ih][oc][r];
  }
  if (lane < 16) {
    shbuf[warp][2112 + lane]      = lsum[0];
    shbuf[warp][2112 + 16 + lane] = lsum[1];
  }
  __syncthreads();

  // merge AW key-split waves; thread (iw, o) handles rows i = iw + 4*rr
  const int o  = tid & 63;
  const int iw = tid >> 6;
  #pragma unroll
  for (int rr = 0; rr < 8; rr++) {
    const int i = iw + rr * 4;
    float L = 0.f, O = 0.f;
    #pragma unroll
    for (int w = 0; w < AW; w++) {
      L += shbuf[w][2112 + i];
      O += shbuf[w][o * 33 + i];
    }
    out[(size_t)(b * TT + i0 + i) * HH + o] = O / L;
  }
}

extern "C" void kernel_launch(void* const* d_in, const int* in_sizes, int n_in,
                              void* d_out, int out_size, void* d_ws, size_t ws_size,
                              hipStream_t stream) {
  const size_t NWP = 3 * 4 * 32 * 64 * 8;      // 196,608 elems wpack
  const size_t NP  = (size_t)BB * TT * HH;     // 4,194,304 elems per pack

  us* wpack = (us*)d_ws;
  us* qpack = wpack + NWP;
  us* kpack = qpack + NP;
  us* vpack = kpack + NP;                      // total ws ~25.5 MB
  float* out = (float*)d_out;

  convertw_kernel<<<96, 256, 0, stream>>>(
      (const float*)d_in[1], (const float*)d_in[2], (const float*)d_in[3], wpack);
  proj_kernel<<<BB * TT / 64, 768, 0, stream>>>(
      (const float*)d_in[0], wpack, qpack, kpack, vpack);
  attn_kernel<<<512, 256, 0, stream>>>(qpack, kpack, vpack, out);
}

// Round 4
// 144.783 us; speedup vs baseline: 1.0960x; 1.0089x over previous
//
#include <hip/hip_runtime.h>

#define BB 4
#define TT 4096
#define CC 1024
#define HH 64
#define AW 4   // attn key-split waves per block

typedef unsigned short us;
typedef us v8u __attribute__((ext_vector_type(8)));
typedef us v4u __attribute__((ext_vector_type(4)));
typedef __bf16 v8bf __attribute__((ext_vector_type(8)));
typedef float v4f __attribute__((ext_vector_type(4)));

// native RNE f32->bf16 (lowers to v_cvt_pk_bf16_f32; 1 instr vs 4-5 VALU bit-trick)
__device__ __forceinline__ us f2bf(float f) {
  return __builtin_bit_cast(us, (__bf16)f);
}
__device__ __forceinline__ v8bf ldb(const us* p) {
  return __builtin_bit_cast(v8bf, *(const v8u*)p);
}

// ---- convert weights fp32 -> fragment-packed bf16: wpack[t][oc][kc][lane][8] ----
__global__ __launch_bounds__(256) void convertw_kernel(const float* __restrict__ Wk,
                                                       const float* __restrict__ Wq,
                                                       const float* __restrict__ Wv,
                                                       us* __restrict__ wpack) {
  const int g = blockIdx.x * 256 + threadIdx.x;   // [0, 3*4*32*64)
  const int t = g >> 13;
  const int rem = g & 8191;
  const int oc = rem >> 11;
  const int kc = (rem >> 6) & 31;
  const int lane = rem & 63;
  const float* W = (t == 0) ? Wq : ((t == 1) ? Wk : Wv);
  const int h  = oc * 16 + (lane & 15);
  const int d0 = kc * 32 + (lane >> 4) * 8;
  const float4* src = (const float4*)(W + h * CC + d0);
  const float4 f0 = src[0], f1 = src[1];
  v8u o;
  o[0]=f2bf(f0.x); o[1]=f2bf(f0.y); o[2]=f2bf(f0.z); o[3]=f2bf(f0.w);
  o[4]=f2bf(f1.x); o[5]=f2bf(f1.y); o[6]=f2bf(f1.z); o[7]=f2bf(f1.w);
  *(v8u*)(wpack + (size_t)g * 8) = o;
}

// Packed activation layouts (bf16):
//  qpack/kpack: [b][tile32][half][dhalf][lane][8]; vpack: [b][tile32][oc][lane][8]

// ---------------- Projection v7b: output-stationary waves, weights read ONCE, 2-pass K ----
// 256 blocks x 768 threads (12 waves). Block owns 64 token rows; wave owns one (tensor,oc)
// output panel with full-K in-register accumulation -> zero cross-wave reduce.
// K split in two 512-wide passes so the x LDS stage is 66,560 B (2 blocks/CU, 6 waves/SIMD).
// Weight frag loaded once per (wave,kc), reused for 4 row-groups.
__global__ __launch_bounds__(768, 6) void proj_kernel(
    const float* __restrict__ x, const us* __restrict__ wpack,
    us* __restrict__ qpack, us* __restrict__ kpack, us* __restrict__ vpack)
{
  __shared__ __align__(16) us xlds[64][520];   // 66,560 B; bank-quad (row+q+4kc)%8 uniform

  const int tid  = threadIdx.x;
  const int lane = tid & 63, w = tid >> 6;
  const int i16 = lane & 15, quad = lane >> 4;
  const int t = w >> 2, oc = w & 3;             // wave -> (tensor, oc) panel
  const int rows0 = blockIdx.x * 64;

  const us* wp = wpack + (size_t)w * 16384 + lane * 8;   // w == t*4+oc
  v4f zero = {0.f, 0.f, 0.f, 0.f};
  v4f acc[4] = {zero, zero, zero, zero};

  #pragma unroll
  for (int ph = 0; ph < 2; ph++) {
    if (ph) __syncthreads();                    // pass-0 reads done before overwrite
    // ---- stage 64 x 512 fp32 -> bf16 LDS, coalesced (128 f4 per row) ----
    const float4* xg4 = (const float4*)(x + (size_t)rows0 * CC + ph * 512);
    for (int i = tid; i < 8192; i += 768) {
      const int r = i >> 7, c = i & 127;
      const float4 f = xg4[r * 256 + c];
      v4u o; o[0]=f2bf(f.x); o[1]=f2bf(f.y); o[2]=f2bf(f.z); o[3]=f2bf(f.w);
      *(v4u*)&xlds[r][c * 4] = o;
    }
    __syncthreads();

    // ---- 16 kc x (1 weight load + 4 ds_read_b128 + 4 MFMA), zero barriers ----
    #pragma unroll 4
    for (int kc = 0; kc < 16; kc++) {
      const v8bf wf = ldb(wp + (ph * 16 + kc) * 512);
      #pragma unroll
      for (int rg = 0; rg < 4; rg++) {
        const v8bf a = ldb(&xlds[rg * 16 + i16][kc * 32 + quad * 8]);
        acc[rg] = __builtin_amdgcn_mfma_f32_16x16x32_bf16(a, wf, acc[rg], 0, 0, 0);
      }
    }
  }

  // ---- epilogue: pack stores (layouts identical to v5) ----
  const float COEF = 0.015625f * 1.4426950408889634f;  // scale^2 * log2(e), folded into q
  const int b     = rows0 >> 12;
  const int tile0 = (rows0 & (TT - 1)) >> 5;

  if (t < 2) {
    us* dst = t ? kpack : qpack;
    const float c = t ? 1.0f : COEF;
    const int h = oc * 16 + i16;
    #pragma unroll
    for (int rg16 = 0; rg16 < 4; rg16++) {
      const int tile = tile0 + (rg16 >> 1);
      const int rg = rg16 & 1;
      #pragma unroll
      for (int r = 0; r < 4; r++) {
        const int tr = quad * 4 + r;
        const int lane2 = tr + 16 * ((h >> 3) & 3);
        const size_t idx = ((((size_t)(b * 128 + tile) * 2 + rg) * 2 + (h >> 5)) * 64 + lane2) * 8 + (h & 7);
        dst[idx] = f2bf(acc[rg16][r] * c);
      }
    }
  } else {
    #pragma unroll
    for (int rg16 = 0; rg16 < 4; rg16++) {
      const int tile = tile0 + (rg16 >> 1);
      const int rg = rg16 & 1;
      const int lane3 = i16 + 16 * (rg * 2 + (quad >> 1));
      v4u pk;
      #pragma unroll
      for (int r = 0; r < 4; r++) pk[r] = f2bf(acc[rg16][r]);
      *(v4u*)&vpack[(((size_t)(b * 128 + tile) * 4 + oc) * 64 + lane3) * 8 + (quad & 1) * 4] = pk;
    }
  }
}

// ---------------- Flash attention v4b: 4-wave blocks, P double-buffer pipeline ----------------
__global__ __launch_bounds__(256) void attn_kernel(
    const us* __restrict__ qpack, const us* __restrict__ kpack,
    const us* __restrict__ vpack, float* __restrict__ out)
{
  // per-wave 2148 floats: loop uses first 1280 (P dbuf us[2][2][16][40]);
  // after loop: O^T [64][33] + lsum[32] at 2112.
  __shared__ float shbuf[AW][2148];

  const int tid  = threadIdx.x;
  const int lane = tid & 63, warp = tid >> 6;
  const int i16 = lane & 15, quad = lane >> 4;

  // pairing: blocks p and p+256 share a CU -> complementary key-range lengths
  const int p = blockIdx.x & 255, s = blockIdx.x >> 8;
  const int b  = p & 3;
  const int q0 = p >> 2;
  const int qb = s ? (127 - q0) : q0;
  const int i0 = qb << 5;
  const int nt = min(qb + 2, 128);

  us* Pw = (us*)shbuf[warp];
  const float NEGINF = -__builtin_inff();

  v8bf qf[2][2];
  #pragma unroll
  for (int ih = 0; ih < 2; ih++)
    #pragma unroll
    for (int g = 0; g < 2; g++)
      qf[ih][g] = ldb(qpack + ((((size_t)(b * 128 + qb) * 2 + ih) * 2 + g) * 64 + lane) * 8);

  v4f zero = {0.f, 0.f, 0.f, 0.f};
  v4f oacc[2][4];
  #pragma unroll
  for (int ih = 0; ih < 2; ih++)
    #pragma unroll
    for (int oc = 0; oc < 4; oc++) oacc[ih][oc] = zero;
  float lsum[2] = {0.f, 0.f};

  auto loadK = [&](int t, v8bf kf[2][2]) {
    #pragma unroll
    for (int f = 0; f < 2; f++)
      #pragma unroll
      for (int g = 0; g < 2; g++)
        kf[f][g] = ldb(kpack + ((((size_t)(b * 128 + t) * 2 + f) * 2 + g) * 64 + lane) * 8);
  };
  auto loadV = [&](int t, v8bf vf[4]) {
    #pragma unroll
    for (int oc = 0; oc < 4; oc++)
      vf[oc] = ldb(vpack + (((size_t)(b * 128 + t) * 4 + oc) * 64 + lane) * 8);
  };
  auto qk_exp_store = [&](int t, const v8bf kf[2][2], int buf) {
    v4f sacc[2][2];
    #pragma unroll
    for (int ih = 0; ih < 2; ih++)
      #pragma unroll
      for (int f = 0; f < 2; f++) {
        v4f sv = zero;
        sv = __builtin_amdgcn_mfma_f32_16x16x32_bf16(kf[f][0], qf[ih][0], sv, 0, 0, 0);
        sv = __builtin_amdgcn_mfma_f32_16x16x32_bf16(kf[f][1], qf[ih][1], sv, 0, 0, 0);
        sacc[ih][f] = sv;
      }
    const int j0 = t * 32;
    const bool needMask = (t >= qb);
    #pragma unroll
    for (int ih = 0; ih < 2; ih++) {
      float ps[8];
      #pragma unroll
      for (int f = 0; f < 2; f++)
        #pragma unroll
        for (int r = 0; r < 4; r++) {
          float sv = fminf(sacc[ih][f][r], 80.f);
          if (needMask) {
            const int j = j0 + f * 16 + quad * 4 + r;
            const int i = i0 + ih * 16 + i16;
            sv = (j <= i + 1) ? sv : NEGINF;
          }
          ps[f * 4 + r] = exp2f(sv);
        }
      // tree-sum: shorter dep chain than 8 serial adds (and more accurate)
      {
        const float s0 = ps[0] + ps[1], s1 = ps[2] + ps[3];
        const float s2 = ps[4] + ps[5], s3 = ps[6] + ps[7];
        lsum[ih] += (s0 + s1) + (s2 + s3);
      }
      #pragma unroll
      for (int f = 0; f < 2; f++) {
        v4u pk;
        #pragma unroll
        for (int r = 0; r < 4; r++) pk[r] = f2bf(ps[f * 4 + r]);
        *(v4u*)&Pw[buf * 1280 + ih * 640 + i16 * 40 + f * 16 + quad * 4] = pk;
      }
    }
  };
  auto pv = [&](int buf, const v8bf vf[4]) {
    #pragma unroll
    for (int ih = 0; ih < 2; ih++) {
      v8bf pf = __builtin_bit_cast(v8bf, *(const v8u*)&Pw[buf * 1280 + ih * 640 + i16 * 40 + quad * 8]);
      #pragma unroll
      for (int oc = 0; oc < 4; oc++)
        oacc[ih][oc] = __builtin_amdgcn_mfma_f32_16x16x32_bf16(vf[oc], pf, oacc[ih][oc], 0, 0, 0);
    }
  };

  // software pipeline: PV(t) uses P stored one iteration earlier (lgkm long retired)
  int t = warp, buf = 0;
  if (t < nt) {
    v8bf kf[2][2], vprev[4];
    loadK(t, kf); loadV(t, vprev);
    qk_exp_store(t, kf, 0);
    for (t += AW; t < nt; t += AW) {
      v8bf kf2[2][2], vnew[4];
      loadK(t, kf2); loadV(t, vnew);
      pv(buf, vprev);                 // reads P(buf) written last iteration
      qk_exp_store(t, kf2, buf ^ 1);  // writes the other buffer
      #pragma unroll
      for (int v = 0; v < 4; v++) vprev[v] = vnew[v];
      buf ^= 1;
    }
    pv(buf, vprev);                   // drain
  }

  // publish per-wave partials
  #pragma unroll
  for (int ih = 0; ih < 2; ih++) {
    lsum[ih] += __shfl_xor(lsum[ih], 16, 64);
    lsum[ih] += __shfl_xor(lsum[ih], 32, 64);
    #pragma unroll
    for (int oc = 0; oc < 4; oc++)
      #pragma unroll
      for (int r = 0; r < 4; r++)
        shbuf[warp][(oc * 16 + quad * 4 + r) * 33 + ih * 16 + i16] = oacc[ih][oc][r];
  }
  if (lane < 16) {
    shbuf[warp][2112 + lane]      = lsum[0];
    shbuf[warp][2112 + 16 + lane] = lsum[1];
  }
  __syncthreads();

  // merge AW key-split waves; thread (iw, o) handles rows i = iw + 4*rr
  const int o  = tid & 63;
  const int iw = tid >> 6;
  #pragma unroll
  for (int rr = 0; rr < 8; rr++) {
    const int i = iw + rr * 4;
    float L = 0.f, O = 0.f;
    #pragma unroll
    for (int w = 0; w < AW; w++) {
      L += shbuf[w][2112 + i];
      O += shbuf[w][o * 33 + i];
    }
    out[(size_t)(b * TT + i0 + i) * HH + o] = O / L;
  }
}

extern "C" void kernel_launch(void* const* d_in, const int* in_sizes, int n_in,
                              void* d_out, int out_size, void* d_ws, size_t ws_size,
                              hipStream_t stream) {
  const size_t NWP = 3 * 4 * 32 * 64 * 8;      // 196,608 elems wpack
  const size_t NP  = (size_t)BB * TT * HH;     // 4,194,304 elems per pack

  us* wpack = (us*)d_ws;
  us* qpack = wpack + NWP;
  us* kpack = qpack + NP;
  us* vpack = kpack + NP;                      // total ws ~25.5 MB
  float* out = (float*)d_out;

  convertw_kernel<<<96, 256, 0, stream>>>(
      (const float*)d_in[1], (const float*)d_in[2], (const float*)d_in[3], wpack);
  proj_kernel<<<BB * TT / 64, 768, 0, stream>>>(
      (const float*)d_in[0], wpack, qpack, kpack, vpack);
  attn_kernel<<<512, 256, 0, stream>>>(qpack, kpack, vpack, out);
}

// Round 5
// 140.823 us; speedup vs baseline: 1.1268x; 1.0281x over previous
//
#include <hip/hip_runtime.h>

#define BB 4
#define TT 4096
#define CC 1024
#define HH 64
#define AW 8   // attn key-split waves per block

typedef unsigned short us;
typedef us v8u __attribute__((ext_vector_type(8)));
typedef us v4u __attribute__((ext_vector_type(4)));
typedef __bf16 v8bf __attribute__((ext_vector_type(8)));
typedef float v4f __attribute__((ext_vector_type(4)));

// native RNE f32->bf16 (lowers to v_cvt_pk_bf16_f32; 1 instr vs 4-5 VALU bit-trick)
__device__ __forceinline__ us f2bf(float f) {
  return __builtin_bit_cast(us, (__bf16)f);
}
__device__ __forceinline__ v8bf ldb(const us* p) {
  return __builtin_bit_cast(v8bf, *(const v8u*)p);
}

// ---- convert weights fp32 -> fragment-packed bf16: wpack[t][oc][kc][lane][8] ----
__global__ __launch_bounds__(256) void convertw_kernel(const float* __restrict__ Wk,
                                                       const float* __restrict__ Wq,
                                                       const float* __restrict__ Wv,
                                                       us* __restrict__ wpack) {
  const int g = blockIdx.x * 256 + threadIdx.x;   // [0, 3*4*32*64)
  const int t = g >> 13;
  const int rem = g & 8191;
  const int oc = rem >> 11;
  const int kc = (rem >> 6) & 31;
  const int lane = rem & 63;
  const float* W = (t == 0) ? Wq : ((t == 1) ? Wk : Wv);
  const int h  = oc * 16 + (lane & 15);
  const int d0 = kc * 32 + (lane >> 4) * 8;
  const float4* src = (const float4*)(W + h * CC + d0);
  const float4 f0 = src[0], f1 = src[1];
  v8u o;
  o[0]=f2bf(f0.x); o[1]=f2bf(f0.y); o[2]=f2bf(f0.z); o[3]=f2bf(f0.w);
  o[4]=f2bf(f1.x); o[5]=f2bf(f1.y); o[6]=f2bf(f1.z); o[7]=f2bf(f1.w);
  *(v8u*)(wpack + (size_t)g * 8) = o;
}

// Packed activation layouts (bf16):
//  qpack/kpack: [b][tile32][half][dhalf][lane][8]; vpack: [b][tile32][oc][lane][8]

// ---------------- Projection v7b: output-stationary waves, weights read ONCE, 2-pass K ----
__global__ __launch_bounds__(768, 6) void proj_kernel(
    const float* __restrict__ x, const us* __restrict__ wpack,
    us* __restrict__ qpack, us* __restrict__ kpack, us* __restrict__ vpack)
{
  __shared__ __align__(16) us xlds[64][520];   // 66,560 B; bank-quad (row+q+4kc)%8 uniform

  const int tid  = threadIdx.x;
  const int lane = tid & 63, w = tid >> 6;
  const int i16 = lane & 15, quad = lane >> 4;
  const int t = w >> 2, oc = w & 3;             // wave -> (tensor, oc) panel
  const int rows0 = blockIdx.x * 64;

  const us* wp = wpack + (size_t)w * 16384 + lane * 8;   // w == t*4+oc
  v4f zero = {0.f, 0.f, 0.f, 0.f};
  v4f acc[4] = {zero, zero, zero, zero};

  #pragma unroll
  for (int ph = 0; ph < 2; ph++) {
    if (ph) __syncthreads();                    // pass-0 reads done before overwrite
    // ---- stage 64 x 512 fp32 -> bf16 LDS, coalesced (128 f4 per row) ----
    const float4* xg4 = (const float4*)(x + (size_t)rows0 * CC + ph * 512);
    for (int i = tid; i < 8192; i += 768) {
      const int r = i >> 7, c = i & 127;
      const float4 f = xg4[r * 256 + c];
      v4u o; o[0]=f2bf(f.x); o[1]=f2bf(f.y); o[2]=f2bf(f.z); o[3]=f2bf(f.w);
      *(v4u*)&xlds[r][c * 4] = o;
    }
    __syncthreads();

    // ---- 16 kc x (1 weight load + 4 ds_read_b128 + 4 MFMA), zero barriers ----
    #pragma unroll 4
    for (int kc = 0; kc < 16; kc++) {
      const v8bf wf = ldb(wp + (ph * 16 + kc) * 512);
      #pragma unroll
      for (int rg = 0; rg < 4; rg++) {
        const v8bf a = ldb(&xlds[rg * 16 + i16][kc * 32 + quad * 8]);
        acc[rg] = __builtin_amdgcn_mfma_f32_16x16x32_bf16(a, wf, acc[rg], 0, 0, 0);
      }
    }
  }

  // ---- epilogue: pack stores (layouts identical to v5) ----
  const float COEF = 0.015625f * 1.4426950408889634f;  // scale^2 * log2(e), folded into q
  const int b     = rows0 >> 12;
  const int tile0 = (rows0 & (TT - 1)) >> 5;

  if (t < 2) {
    us* dst = t ? kpack : qpack;
    const float c = t ? 1.0f : COEF;
    const int h = oc * 16 + i16;
    #pragma unroll
    for (int rg16 = 0; rg16 < 4; rg16++) {
      const int tile = tile0 + (rg16 >> 1);
      const int rg = rg16 & 1;
      #pragma unroll
      for (int r = 0; r < 4; r++) {
        const int tr = quad * 4 + r;
        const int lane2 = tr + 16 * ((h >> 3) & 3);
        const size_t idx = ((((size_t)(b * 128 + tile) * 2 + rg) * 2 + (h >> 5)) * 64 + lane2) * 8 + (h & 7);
        dst[idx] = f2bf(acc[rg16][r] * c);
      }
    }
  } else {
    #pragma unroll
    for (int rg16 = 0; rg16 < 4; rg16++) {
      const int tile = tile0 + (rg16 >> 1);
      const int rg = rg16 & 1;
      const int lane3 = i16 + 16 * (rg * 2 + (quad >> 1));
      v4u pk;
      #pragma unroll
      for (int r = 0; r < 4; r++) pk[r] = f2bf(acc[rg16][r]);
      *(v4u*)&vpack[(((size_t)(b * 128 + tile) * 4 + oc) * 64 + lane3) * 8 + (quad & 1) * 4] = pk;
    }
  }
}

// ---------------- Flash attention v5: 8-wave key-split + K/V one-iteration prefetch ----------
// Long (qb~127) blocks previously ran 4 waves (1/SIMD) with K load latency exposed in-iteration.
// Now: 512 threads, AW=8 (max iters/wave 32->16, 2 waves/SIMD for long blocks' lifetime), and
// K/V for tile t+AW are loaded one full iteration before use (whole body covers the latency).
__global__ __launch_bounds__(512) void attn_kernel(
    const us* __restrict__ qpack, const us* __restrict__ kpack,
    const us* __restrict__ vpack, float* __restrict__ out)
{
  // per-wave 2148 floats: loop uses first 1280 (P dbuf us[2][2][16][40]);
  // after loop: O^T [64][33] + lsum[32] at 2112. Total 68,736 B.
  __shared__ float shbuf[AW][2148];

  const int tid  = threadIdx.x;
  const int lane = tid & 63, warp = tid >> 6;
  const int i16 = lane & 15, quad = lane >> 4;

  // pairing: blocks p and p+256 see complementary key-range lengths
  const int p = blockIdx.x & 255, s = blockIdx.x >> 8;
  const int b  = p & 3;
  const int q0 = p >> 2;
  const int qb = s ? (127 - q0) : q0;
  const int i0 = qb << 5;
  const int nt = min(qb + 2, 128);

  us* Pw = (us*)shbuf[warp];
  const float NEGINF = -__builtin_inff();

  v8bf qf[2][2];
  #pragma unroll
  for (int ih = 0; ih < 2; ih++)
    #pragma unroll
    for (int g = 0; g < 2; g++)
      qf[ih][g] = ldb(qpack + ((((size_t)(b * 128 + qb) * 2 + ih) * 2 + g) * 64 + lane) * 8);

  v4f zero = {0.f, 0.f, 0.f, 0.f};
  v4f oacc[2][4];
  #pragma unroll
  for (int ih = 0; ih < 2; ih++)
    #pragma unroll
    for (int oc = 0; oc < 4; oc++) oacc[ih][oc] = zero;
  float lsum[2] = {0.f, 0.f};

  auto loadK = [&](int t, v8bf kf[2][2]) {
    #pragma unroll
    for (int f = 0; f < 2; f++)
      #pragma unroll
      for (int g = 0; g < 2; g++)
        kf[f][g] = ldb(kpack + ((((size_t)(b * 128 + t) * 2 + f) * 2 + g) * 64 + lane) * 8);
  };
  auto loadV = [&](int t, v8bf vf[4]) {
    #pragma unroll
    for (int oc = 0; oc < 4; oc++)
      vf[oc] = ldb(vpack + (((size_t)(b * 128 + t) * 4 + oc) * 64 + lane) * 8);
  };
  auto qk_exp_store = [&](int t, const v8bf kf[2][2], int buf) {
    v4f sacc[2][2];
    #pragma unroll
    for (int ih = 0; ih < 2; ih++)
      #pragma unroll
      for (int f = 0; f < 2; f++) {
        v4f sv = zero;
        sv = __builtin_amdgcn_mfma_f32_16x16x32_bf16(kf[f][0], qf[ih][0], sv, 0, 0, 0);
        sv = __builtin_amdgcn_mfma_f32_16x16x32_bf16(kf[f][1], qf[ih][1], sv, 0, 0, 0);
        sacc[ih][f] = sv;
      }
    const int j0 = t * 32;
    const bool needMask = (t >= qb);
    #pragma unroll
    for (int ih = 0; ih < 2; ih++) {
      float ps[8];
      #pragma unroll
      for (int f = 0; f < 2; f++)
        #pragma unroll
        for (int r = 0; r < 4; r++) {
          float sv = fminf(sacc[ih][f][r], 80.f);
          if (needMask) {
            const int j = j0 + f * 16 + quad * 4 + r;
            const int i = i0 + ih * 16 + i16;
            sv = (j <= i + 1) ? sv : NEGINF;
          }
          ps[f * 4 + r] = exp2f(sv);
        }
      // tree-sum: shorter dep chain than 8 serial adds (and more accurate)
      {
        const float s0 = ps[0] + ps[1], s1 = ps[2] + ps[3];
        const float s2 = ps[4] + ps[5], s3 = ps[6] + ps[7];
        lsum[ih] += (s0 + s1) + (s2 + s3);
      }
      #pragma unroll
      for (int f = 0; f < 2; f++) {
        v4u pk;
        #pragma unroll
        for (int r = 0; r < 4; r++) pk[r] = f2bf(ps[f * 4 + r]);
        *(v4u*)&Pw[buf * 1280 + ih * 640 + i16 * 40 + f * 16 + quad * 4] = pk;
      }
    }
  };
  auto pv = [&](int buf, const v8bf vf[4]) {
    #pragma unroll
    for (int ih = 0; ih < 2; ih++) {
      v8bf pf = __builtin_bit_cast(v8bf, *(const v8u*)&Pw[buf * 1280 + ih * 640 + i16 * 40 + quad * 8]);
      #pragma unroll
      for (int oc = 0; oc < 4; oc++)
        oacc[ih][oc] = __builtin_amdgcn_mfma_f32_16x16x32_bf16(vf[oc], pf, oacc[ih][oc], 0, 0, 0);
    }
  };

  // software pipeline:
  //   - P double-buffer: PV(t) consumes P stored one iteration earlier
  //   - K/V prefetch: tile t+AW loaded one full iteration before its qk (latency hidden)
  int t = warp, buf = 0;
  if (t < nt) {
    v8bf kcur[2][2], vcur[4], knxt[2][2], vnxt[4];
    loadK(t, kcur); loadV(t, vcur);
    if (t + AW < nt) { loadK(t + AW, knxt); loadV(t + AW, vnxt); }
    qk_exp_store(t, kcur, 0);        // first tile: load exposure unavoidable
    #pragma unroll 2
    for (t += AW; t < nt; t += AW) {
      pv(buf, vcur);                 // O += P(t-AW) * V(t-AW); frees cur slots
      #pragma unroll
      for (int f = 0; f < 2; f++)
        #pragma unroll
        for (int g = 0; g < 2; g++) kcur[f][g] = knxt[f][g];
      #pragma unroll
      for (int v = 0; v < 4; v++) vcur[v] = vnxt[v];
      if (t + AW < nt) { loadK(t + AW, knxt); loadV(t + AW, vnxt); }
      qk_exp_store(t, kcur, buf ^ 1);  // K(t) was loaded last iteration
      buf ^= 1;
    }
    pv(buf, vcur);                   // drain
  }

  // publish per-wave partials
  #pragma unroll
  for (int ih = 0; ih < 2; ih++) {
    lsum[ih] += __shfl_xor(lsum[ih], 16, 64);
    lsum[ih] += __shfl_xor(lsum[ih], 32, 64);
    #pragma unroll
    for (int oc = 0; oc < 4; oc++)
      #pragma unroll
      for (int r = 0; r < 4; r++)
        shbuf[warp][(oc * 16 + quad * 4 + r) * 33 + ih * 16 + i16] = oacc[ih][oc][r];
  }
  if (lane < 16) {
    shbuf[warp][2112 + lane]      = lsum[0];
    shbuf[warp][2112 + 16 + lane] = lsum[1];
  }
  __syncthreads();

  // merge AW=8 key-split waves; thread (iw, o) handles rows i = iw + 8*rr
  const int o  = tid & 63;
  const int iw = tid >> 6;
  #pragma unroll
  for (int rr = 0; rr < 4; rr++) {
    const int i = iw + rr * 8;
    float L = 0.f, O = 0.f;
    #pragma unroll
    for (int w = 0; w < AW; w++) {
      L += shbuf[w][2112 + i];
      O += shbuf[w][o * 33 + i];
    }
    out[(size_t)(b * TT + i0 + i) * HH + o] = O / L;
  }
}

extern "C" void kernel_launch(void* const* d_in, const int* in_sizes, int n_in,
                              void* d_out, int out_size, void* d_ws, size_t ws_size,
                              hipStream_t stream) {
  const size_t NWP = 3 * 4 * 32 * 64 * 8;      // 196,608 elems wpack
  const size_t NP  = (size_t)BB * TT * HH;     // 4,194,304 elems per pack

  us* wpack = (us*)d_ws;
  us* qpack = wpack + NWP;
  us* kpack = qpack + NP;
  us* vpack = kpack + NP;                      // total ws ~25.5 MB
  float* out = (float*)d_out;

  convertw_kernel<<<96, 256, 0, stream>>>(
      (const float*)d_in[1], (const float*)d_in[2], (const float*)d_in[3], wpack);
  proj_kernel<<<BB * TT / 64, 768, 0, stream>>>(
      (const float*)d_in[0], wpack, qpack, kpack, vpack);
  attn_kernel<<<512, 512, 0, stream>>>(qpack, kpack, vpack, out);
}

// Round 6
// 131.261 us; speedup vs baseline: 1.2089x; 1.0728x over previous
//
#include <hip/hip_runtime.h>

#define BB 4
#define TT 4096
#define CC 1024
#define HH 64
#define AW 8   // attn key-split waves per block

typedef unsigned short us;
typedef us v8u __attribute__((ext_vector_type(8)));
typedef us v4u __attribute__((ext_vector_type(4)));
typedef __bf16 v8bf __attribute__((ext_vector_type(8)));
typedef float v4f __attribute__((ext_vector_type(4)));

// native RNE f32->bf16 (lowers to v_cvt_pk_bf16_f32; 1 instr vs 4-5 VALU bit-trick)
__device__ __forceinline__ us f2bf(float f) {
  return __builtin_bit_cast(us, (__bf16)f);
}
__device__ __forceinline__ v8bf ldb(const us* p) {
  return __builtin_bit_cast(v8bf, *(const v8u*)p);
}

// ---- convert weights fp32 -> fragment-packed bf16: wpack[t][oc][kc][lane][8] ----
__global__ __launch_bounds__(256) void convertw_kernel(const float* __restrict__ Wk,
                                                       const float* __restrict__ Wq,
                                                       const float* __restrict__ Wv,
                                                       us* __restrict__ wpack) {
  const int g = blockIdx.x * 256 + threadIdx.x;   // [0, 3*4*32*64)
  const int t = g >> 13;
  const int rem = g & 8191;
  const int oc = rem >> 11;
  const int kc = (rem >> 6) & 31;
  const int lane = rem & 63;
  const float* W = (t == 0) ? Wq : ((t == 1) ? Wk : Wv);
  const int h  = oc * 16 + (lane & 15);
  const int d0 = kc * 32 + (lane >> 4) * 8;
  const float4* src = (const float4*)(W + h * CC + d0);
  const float4 f0 = src[0], f1 = src[1];
  v8u o;
  o[0]=f2bf(f0.x); o[1]=f2bf(f0.y); o[2]=f2bf(f0.z); o[3]=f2bf(f0.w);
  o[4]=f2bf(f1.x); o[5]=f2bf(f1.y); o[6]=f2bf(f1.z); o[7]=f2bf(f1.w);
  *(v8u*)(wpack + (size_t)g * 8) = o;
}

// Packed activation layouts (bf16):
//  qpack/kpack: [b][tile32][half][dhalf][lane][8]; vpack: [b][tile32][oc][lane][8]

// ---------------- Projection v8: 32-row blocks, 2 resident/CU, single-pass stage ------------
// 512 blocks x 768 threads (12 waves). Block owns 32 token rows; wave owns one (tensor,oc)
// output panel with full-K in-register accumulation. Whole 32x1024 x-tile staged once
// (67,072 B LDS -> 2 blocks/CU co-resident: one block's HBM stage overlaps the other's
// compute, fixing v7b's serial stage|compute phases at 1 block/CU). One barrier total.
// Frag-read bank math: row stride 2096 B -> dBank/row=12 -> 8 spans x 8 lanes, uniform.
__global__ __launch_bounds__(768, 6) void proj_kernel(
    const float* __restrict__ x, const us* __restrict__ wpack,
    us* __restrict__ qpack, us* __restrict__ kpack, us* __restrict__ vpack)
{
  __shared__ __align__(16) us xlds[32][1048];   // 67,072 B

  const int tid  = threadIdx.x;
  const int lane = tid & 63, w = tid >> 6;
  const int i16 = lane & 15, quad = lane >> 4;
  const int t = w >> 2, oc = w & 3;             // wave -> (tensor, oc) panel
  const int rows0 = blockIdx.x * 32;

  // ---- stage 32 x 1024 fp32 -> bf16 LDS once, fully coalesced (256 f4 per row) ----
  const float4* xg4 = (const float4*)(x + (size_t)rows0 * CC);
  for (int i = tid; i < 8192; i += 768) {
    const float4 f = xg4[i];
    v4u o; o[0]=f2bf(f.x); o[1]=f2bf(f.y); o[2]=f2bf(f.z); o[3]=f2bf(f.w);
    *(v4u*)&xlds[i >> 8][(i & 255) * 4] = o;
  }
  __syncthreads();

  // ---- full-K, barrier-free: 32 kc x (1 weight load + 2 ds_read_b128 + 2 MFMA) ----
  const us* wp = wpack + (size_t)w * 16384 + lane * 8;   // w == t*4+oc
  v4f zero = {0.f, 0.f, 0.f, 0.f};
  v4f acc[2] = {zero, zero};

  #pragma unroll 4
  for (int kc = 0; kc < 32; kc++) {
    const v8bf wf = ldb(wp + kc * 512);
    #pragma unroll
    for (int rg = 0; rg < 2; rg++) {
      const v8bf a = ldb(&xlds[rg * 16 + i16][kc * 32 + quad * 8]);
      acc[rg] = __builtin_amdgcn_mfma_f32_16x16x32_bf16(a, wf, acc[rg], 0, 0, 0);
    }
  }

  // ---- epilogue: pack stores (layouts identical to v7b, collapsed to one tile) ----
  const float COEF = 0.015625f * 1.4426950408889634f;  // scale^2 * log2(e), folded into q
  const int b    = rows0 >> 12;
  const int tile = (rows0 & (TT - 1)) >> 5;

  if (t < 2) {
    us* dst = t ? kpack : qpack;
    const float c = t ? 1.0f : COEF;
    const int h = oc * 16 + i16;
    #pragma unroll
    for (int rg = 0; rg < 2; rg++) {
      #pragma unroll
      for (int r = 0; r < 4; r++) {
        const int tr = quad * 4 + r;
        const int lane2 = tr + 16 * ((h >> 3) & 3);
        const size_t idx = ((((size_t)(b * 128 + tile) * 2 + rg) * 2 + (h >> 5)) * 64 + lane2) * 8 + (h & 7);
        dst[idx] = f2bf(acc[rg][r] * c);
      }
    }
  } else {
    #pragma unroll
    for (int rg = 0; rg < 2; rg++) {
      const int lane3 = i16 + 16 * (rg * 2 + (quad >> 1));
      v4u pk;
      #pragma unroll
      for (int r = 0; r < 4; r++) pk[r] = f2bf(acc[rg][r]);
      *(v4u*)&vpack[(((size_t)(b * 128 + tile) * 4 + oc) * 64 + lane3) * 8 + (quad & 1) * 4] = pk;
    }
  }
}

// ---------------- Flash attention v5: 8-wave key-split + K/V one-iteration prefetch ----------
__global__ __launch_bounds__(512) void attn_kernel(
    const us* __restrict__ qpack, const us* __restrict__ kpack,
    const us* __restrict__ vpack, float* __restrict__ out)
{
  // per-wave 2148 floats: loop uses first 1280 (P dbuf us[2][2][16][40]);
  // after loop: O^T [64][33] + lsum[32] at 2112. Total 68,736 B.
  __shared__ float shbuf[AW][2148];

  const int tid  = threadIdx.x;
  const int lane = tid & 63, warp = tid >> 6;
  const int i16 = lane & 15, quad = lane >> 4;

  // pairing: blocks p and p+256 see complementary key-range lengths
  const int p = blockIdx.x & 255, s = blockIdx.x >> 8;
  const int b  = p & 3;
  const int q0 = p >> 2;
  const int qb = s ? (127 - q0) : q0;
  const int i0 = qb << 5;
  const int nt = min(qb + 2, 128);

  us* Pw = (us*)shbuf[warp];
  const float NEGINF = -__builtin_inff();

  v8bf qf[2][2];
  #pragma unroll
  for (int ih = 0; ih < 2; ih++)
    #pragma unroll
    for (int g = 0; g < 2; g++)
      qf[ih][g] = ldb(qpack + ((((size_t)(b * 128 + qb) * 2 + ih) * 2 + g) * 64 + lane) * 8);

  v4f zero = {0.f, 0.f, 0.f, 0.f};
  v4f oacc[2][4];
  #pragma unroll
  for (int ih = 0; ih < 2; ih++)
    #pragma unroll
    for (int oc = 0; oc < 4; oc++) oacc[ih][oc] = zero;
  float lsum[2] = {0.f, 0.f};

  auto loadK = [&](int t, v8bf kf[2][2]) {
    #pragma unroll
    for (int f = 0; f < 2; f++)
      #pragma unroll
      for (int g = 0; g < 2; g++)
        kf[f][g] = ldb(kpack + ((((size_t)(b * 128 + t) * 2 + f) * 2 + g) * 64 + lane) * 8);
  };
  auto loadV = [&](int t, v8bf vf[4]) {
    #pragma unroll
    for (int oc = 0; oc < 4; oc++)
      vf[oc] = ldb(vpack + (((size_t)(b * 128 + t) * 4 + oc) * 64 + lane) * 8);
  };
  auto qk_exp_store = [&](int t, const v8bf kf[2][2], int buf) {
    v4f sacc[2][2];
    #pragma unroll
    for (int ih = 0; ih < 2; ih++)
      #pragma unroll
      for (int f = 0; f < 2; f++) {
        v4f sv = zero;
        sv = __builtin_amdgcn_mfma_f32_16x16x32_bf16(kf[f][0], qf[ih][0], sv, 0, 0, 0);
        sv = __builtin_amdgcn_mfma_f32_16x16x32_bf16(kf[f][1], qf[ih][1], sv, 0, 0, 0);
        sacc[ih][f] = sv;
      }
    const int j0 = t * 32;
    const bool needMask = (t >= qb);
    #pragma unroll
    for (int ih = 0; ih < 2; ih++) {
      float ps[8];
      #pragma unroll
      for (int f = 0; f < 2; f++)
        #pragma unroll
        for (int r = 0; r < 4; r++) {
          float sv = fminf(sacc[ih][f][r], 80.f);
          if (needMask) {
            const int j = j0 + f * 16 + quad * 4 + r;
            const int i = i0 + ih * 16 + i16;
            sv = (j <= i + 1) ? sv : NEGINF;
          }
          ps[f * 4 + r] = exp2f(sv);
        }
      // tree-sum: shorter dep chain than 8 serial adds (and more accurate)
      {
        const float s0 = ps[0] + ps[1], s1 = ps[2] + ps[3];
        const float s2 = ps[4] + ps[5], s3 = ps[6] + ps[7];
        lsum[ih] += (s0 + s1) + (s2 + s3);
      }
      #pragma unroll
      for (int f = 0; f < 2; f++) {
        v4u pk;
        #pragma unroll
        for (int r = 0; r < 4; r++) pk[r] = f2bf(ps[f * 4 + r]);
        *(v4u*)&Pw[buf * 1280 + ih * 640 + i16 * 40 + f * 16 + quad * 4] = pk;
      }
    }
  };
  auto pv = [&](int buf, const v8bf vf[4]) {
    #pragma unroll
    for (int ih = 0; ih < 2; ih++) {
      v8bf pf = __builtin_bit_cast(v8bf, *(const v8u*)&Pw[buf * 1280 + ih * 640 + i16 * 40 + quad * 8]);
      #pragma unroll
      for (int oc = 0; oc < 4; oc++)
        oacc[ih][oc] = __builtin_amdgcn_mfma_f32_16x16x32_bf16(vf[oc], pf, oacc[ih][oc], 0, 0, 0);
    }
  };

  // software pipeline:
  //   - P double-buffer: PV(t) consumes P stored one iteration earlier
  //   - K/V prefetch: tile t+AW loaded one full iteration before its qk (latency hidden)
  int t = warp, buf = 0;
  if (t < nt) {
    v8bf kcur[2][2], vcur[4], knxt[2][2], vnxt[4];
    loadK(t, kcur); loadV(t, vcur);
    if (t + AW < nt) { loadK(t + AW, knxt); loadV(t + AW, vnxt); }
    qk_exp_store(t, kcur, 0);        // first tile: load exposure unavoidable
    #pragma unroll 2
    for (t += AW; t < nt; t += AW) {
      pv(buf, vcur);                 // O += P(t-AW) * V(t-AW); frees cur slots
      #pragma unroll
      for (int f = 0; f < 2; f++)
        #pragma unroll
        for (int g = 0; g < 2; g++) kcur[f][g] = knxt[f][g];
      #pragma unroll
      for (int v = 0; v < 4; v++) vcur[v] = vnxt[v];
      if (t + AW < nt) { loadK(t + AW, knxt); loadV(t + AW, vnxt); }
      qk_exp_store(t, kcur, buf ^ 1);  // K(t) was loaded last iteration
      buf ^= 1;
    }
    pv(buf, vcur);                   // drain
  }

  // publish per-wave partials
  #pragma unroll
  for (int ih = 0; ih < 2; ih++) {
    lsum[ih] += __shfl_xor(lsum[ih], 16, 64);
    lsum[ih] += __shfl_xor(lsum[ih], 32, 64);
    #pragma unroll
    for (int oc = 0; oc < 4; oc++)
      #pragma unroll
      for (int r = 0; r < 4; r++)
        shbuf[warp][(oc * 16 + quad * 4 + r) * 33 + ih * 16 + i16] = oacc[ih][oc][r];
  }
  if (lane < 16) {
    shbuf[warp][2112 + lane]      = lsum[0];
    shbuf[warp][2112 + 16 + lane] = lsum[1];
  }
  __syncthreads();

  // merge AW=8 key-split waves; thread (iw, o) handles rows i = iw + 8*rr
  const int o  = tid & 63;
  const int iw = tid >> 6;
  #pragma unroll
  for (int rr = 0; rr < 4; rr++) {
    const int i = iw + rr * 8;
    float L = 0.f, O = 0.f;
    #pragma unroll
    for (int w = 0; w < AW; w++) {
      L += shbuf[w][2112 + i];
      O += shbuf[w][o * 33 + i];
    }
    out[(size_t)(b * TT + i0 + i) * HH + o] = O / L;
  }
}

extern "C" void kernel_launch(void* const* d_in, const int* in_sizes, int n_in,
                              void* d_out, int out_size, void* d_ws, size_t ws_size,
                              hipStream_t stream) {
  const size_t NWP = 3 * 4 * 32 * 64 * 8;      // 196,608 elems wpack
  const size_t NP  = (size_t)BB * TT * HH;     // 4,194,304 elems per pack

  us* wpack = (us*)d_ws;
  us* qpack = wpack + NWP;
  us* kpack = qpack + NP;
  us* vpack = kpack + NP;                      // total ws ~25.5 MB
  float* out = (float*)d_out;

  convertw_kernel<<<96, 256, 0, stream>>>(
      (const float*)d_in[1], (const float*)d_in[2], (const float*)d_in[3], wpack);
  proj_kernel<<<BB * TT / 32, 768, 0, stream>>>(
      (const float*)d_in[0], wpack, qpack, kpack, vpack);
  attn_kernel<<<512, 512, 0, stream>>>(qpack, kpack, vpack, out);
}

// Round 7
// 127.452 us; speedup vs baseline: 1.2450x; 1.0299x over previous
//
#include <hip/hip_runtime.h>

#define BB 4
#define TT 4096
#define CC 1024
#define HH 64
#define AW 8   // attn key-split waves per block

typedef unsigned short us;
typedef us v8u __attribute__((ext_vector_type(8)));
typedef us v4u __attribute__((ext_vector_type(4)));
typedef __bf16 v8bf __attribute__((ext_vector_type(8)));
typedef float v4f __attribute__((ext_vector_type(4)));

// native RNE f32->bf16 (lowers to v_cvt_pk_bf16_f32; 1 instr vs 4-5 VALU bit-trick)
__device__ __forceinline__ us f2bf(float f) {
  return __builtin_bit_cast(us, (__bf16)f);
}
__device__ __forceinline__ v8bf ldb(const us* p) {
  return __builtin_bit_cast(v8bf, *(const v8u*)p);
}

// ---- convert weights fp32 -> fragment-packed bf16: wpack[t][oc][kc][lane][8] ----
__global__ __launch_bounds__(256) void convertw_kernel(const float* __restrict__ Wk,
                                                       const float* __restrict__ Wq,
                                                       const float* __restrict__ Wv,
                                                       us* __restrict__ wpack) {
  const int g = blockIdx.x * 256 + threadIdx.x;   // [0, 3*4*32*64)
  const int t = g >> 13;
  const int rem = g & 8191;
  const int oc = rem >> 11;
  const int kc = (rem >> 6) & 31;
  const int lane = rem & 63;
  const float* W = (t == 0) ? Wq : ((t == 1) ? Wk : Wv);
  const int h  = oc * 16 + (lane & 15);
  const int d0 = kc * 32 + (lane >> 4) * 8;
  const float4* src = (const float4*)(W + h * CC + d0);
  const float4 f0 = src[0], f1 = src[1];
  v8u o;
  o[0]=f2bf(f0.x); o[1]=f2bf(f0.y); o[2]=f2bf(f0.z); o[3]=f2bf(f0.w);
  o[4]=f2bf(f1.x); o[5]=f2bf(f1.y); o[6]=f2bf(f1.z); o[7]=f2bf(f1.w);
  *(v8u*)(wpack + (size_t)g * 8) = o;
}

// Packed activation layouts (bf16):
//  qpack/kpack: [b][tile32][half][dhalf][lane][8]; vpack: [b][tile32][oc][lane][8]

// ---------------- Projection v8: 32-row blocks, 2 resident/CU, single-pass stage ------------
__global__ __launch_bounds__(768, 6) void proj_kernel(
    const float* __restrict__ x, const us* __restrict__ wpack,
    us* __restrict__ qpack, us* __restrict__ kpack, us* __restrict__ vpack)
{
  __shared__ __align__(16) us xlds[32][1048];   // 67,072 B

  const int tid  = threadIdx.x;
  const int lane = tid & 63, w = tid >> 6;
  const int i16 = lane & 15, quad = lane >> 4;
  const int t = w >> 2, oc = w & 3;             // wave -> (tensor, oc) panel
  const int rows0 = blockIdx.x * 32;

  // ---- stage 32 x 1024 fp32 -> bf16 LDS once, fully coalesced (256 f4 per row) ----
  const float4* xg4 = (const float4*)(x + (size_t)rows0 * CC);
  for (int i = tid; i < 8192; i += 768) {
    const float4 f = xg4[i];
    v4u o; o[0]=f2bf(f.x); o[1]=f2bf(f.y); o[2]=f2bf(f.z); o[3]=f2bf(f.w);
    *(v4u*)&xlds[i >> 8][(i & 255) * 4] = o;
  }
  __syncthreads();

  // ---- full-K, barrier-free: 32 kc x (1 weight load + 2 ds_read_b128 + 2 MFMA) ----
  const us* wp = wpack + (size_t)w * 16384 + lane * 8;   // w == t*4+oc
  v4f zero = {0.f, 0.f, 0.f, 0.f};
  v4f acc[2] = {zero, zero};

  #pragma unroll 4
  for (int kc = 0; kc < 32; kc++) {
    const v8bf wf = ldb(wp + kc * 512);
    #pragma unroll
    for (int rg = 0; rg < 2; rg++) {
      const v8bf a = ldb(&xlds[rg * 16 + i16][kc * 32 + quad * 8]);
      acc[rg] = __builtin_amdgcn_mfma_f32_16x16x32_bf16(a, wf, acc[rg], 0, 0, 0);
    }
  }

  // ---- epilogue: pack stores (layouts identical to v7b, collapsed to one tile) ----
  const float COEF = 0.015625f * 1.4426950408889634f;  // scale^2 * log2(e), folded into q
  const int b    = rows0 >> 12;
  const int tile = (rows0 & (TT - 1)) >> 5;

  if (t < 2) {
    us* dst = t ? kpack : qpack;
    const float c = t ? 1.0f : COEF;
    const int h = oc * 16 + i16;
    #pragma unroll
    for (int rg = 0; rg < 2; rg++) {
      #pragma unroll
      for (int r = 0; r < 4; r++) {
        const int tr = quad * 4 + r;
        const int lane2 = tr + 16 * ((h >> 3) & 3);
        const size_t idx = ((((size_t)(b * 128 + tile) * 2 + rg) * 2 + (h >> 5)) * 64 + lane2) * 8 + (h & 7);
        dst[idx] = f2bf(acc[rg][r] * c);
      }
    }
  } else {
    #pragma unroll
    for (int rg = 0; rg < 2; rg++) {
      const int lane3 = i16 + 16 * (rg * 2 + (quad >> 1));
      v4u pk;
      #pragma unroll
      for (int r = 0; r < 4; r++) pk[r] = f2bf(acc[rg][r]);
      *(v4u*)&vpack[(((size_t)(b * 128 + tile) * 4 + oc) * 64 + lane3) * 8 + (quad & 1) * 4] = pk;
    }
  }
}

// ---------------- Flash attention v6: 8-wave key-split, 128-VGPR cap -> 2 blocks/CU ----------
// v5 used ~170 VGPR -> 1 block/CU: short/long pairing broken (shorts all retire first),
// long blocks ran 16 serial iters at 2 waves/SIMD. v6 caps at 128 VGPR (launch_bounds 512,4)
// with a slimmer pipeline: K prefetched one iter ahead (kcur/knxt rotate); V(t) loaded into
// the slot freed by pv() and consumed one iteration later (single V buffer, -16 VGPR).
__global__ __launch_bounds__(512, 4) void attn_kernel(
    const us* __restrict__ qpack, const us* __restrict__ kpack,
    const us* __restrict__ vpack, float* __restrict__ out)
{
  // per-wave 2148 floats: loop uses first 1280 (P dbuf us[2][2][16][40]);
  // after loop: O^T [64][33] + lsum[32] at 2112. Total 68,736 B (2 blocks = 137 KB <= 160).
  __shared__ float shbuf[AW][2148];

  const int tid  = threadIdx.x;
  const int lane = tid & 63, warp = tid >> 6;
  const int i16 = lane & 15, quad = lane >> 4;

  // pairing: blocks p and p+256 land on the same CU (same XCD, slots 0/1) with
  // complementary key-range lengths -> balanced per-CU work when 2 blocks co-reside
  const int p = blockIdx.x & 255, s = blockIdx.x >> 8;
  const int b  = p & 3;
  const int q0 = p >> 2;
  const int qb = s ? (127 - q0) : q0;
  const int i0 = qb << 5;
  const int nt = min(qb + 2, 128);

  us* Pw = (us*)shbuf[warp];
  const float NEGINF = -__builtin_inff();

  v8bf qf[2][2];
  #pragma unroll
  for (int ih = 0; ih < 2; ih++)
    #pragma unroll
    for (int g = 0; g < 2; g++)
      qf[ih][g] = ldb(qpack + ((((size_t)(b * 128 + qb) * 2 + ih) * 2 + g) * 64 + lane) * 8);

  v4f zero = {0.f, 0.f, 0.f, 0.f};
  v4f oacc[2][4];
  #pragma unroll
  for (int ih = 0; ih < 2; ih++)
    #pragma unroll
    for (int oc = 0; oc < 4; oc++) oacc[ih][oc] = zero;
  float lsum[2] = {0.f, 0.f};

  auto loadK = [&](int t, v8bf kf[2][2]) {
    #pragma unroll
    for (int f = 0; f < 2; f++)
      #pragma unroll
      for (int g = 0; g < 2; g++)
        kf[f][g] = ldb(kpack + ((((size_t)(b * 128 + t) * 2 + f) * 2 + g) * 64 + lane) * 8);
  };
  auto loadV = [&](int t, v8bf vf[4]) {
    #pragma unroll
    for (int oc = 0; oc < 4; oc++)
      vf[oc] = ldb(vpack + (((size_t)(b * 128 + t) * 4 + oc) * 64 + lane) * 8);
  };
  auto qk_exp_store = [&](int t, const v8bf kf[2][2], int buf) {
    v4f sacc[2][2];
    #pragma unroll
    for (int ih = 0; ih < 2; ih++)
      #pragma unroll
      for (int f = 0; f < 2; f++) {
        v4f sv = zero;
        sv = __builtin_amdgcn_mfma_f32_16x16x32_bf16(kf[f][0], qf[ih][0], sv, 0, 0, 0);
        sv = __builtin_amdgcn_mfma_f32_16x16x32_bf16(kf[f][1], qf[ih][1], sv, 0, 0, 0);
        sacc[ih][f] = sv;
      }
    const int j0 = t * 32;
    const bool needMask = (t >= qb);
    #pragma unroll
    for (int ih = 0; ih < 2; ih++) {
      float ps[8];
      #pragma unroll
      for (int f = 0; f < 2; f++)
        #pragma unroll
        for (int r = 0; r < 4; r++) {
          float sv = fminf(sacc[ih][f][r], 80.f);
          if (needMask) {
            const int j = j0 + f * 16 + quad * 4 + r;
            const int i = i0 + ih * 16 + i16;
            sv = (j <= i + 1) ? sv : NEGINF;
          }
          ps[f * 4 + r] = exp2f(sv);
        }
      // tree-sum: shorter dep chain than 8 serial adds (and more accurate)
      {
        const float s0 = ps[0] + ps[1], s1 = ps[2] + ps[3];
        const float s2 = ps[4] + ps[5], s3 = ps[6] + ps[7];
        lsum[ih] += (s0 + s1) + (s2 + s3);
      }
      #pragma unroll
      for (int f = 0; f < 2; f++) {
        v4u pk;
        #pragma unroll
        for (int r = 0; r < 4; r++) pk[r] = f2bf(ps[f * 4 + r]);
        *(v4u*)&Pw[buf * 1280 + ih * 640 + i16 * 40 + f * 16 + quad * 4] = pk;
      }
    }
  };
  auto pv = [&](int buf, const v8bf vf[4]) {
    #pragma unroll
    for (int ih = 0; ih < 2; ih++) {
      v8bf pf = __builtin_bit_cast(v8bf, *(const v8u*)&Pw[buf * 1280 + ih * 640 + i16 * 40 + quad * 8]);
      #pragma unroll
      for (int oc = 0; oc < 4; oc++)
        oacc[ih][oc] = __builtin_amdgcn_mfma_f32_16x16x32_bf16(vf[oc], pf, oacc[ih][oc], 0, 0, 0);
    }
  };

  // software pipeline (register-lean):
  //   P double-buffer: pv(t-AW) consumes P stored one iteration earlier
  //   K: kcur/knxt rotate, loaded one full iteration before qk
  //   V: loaded right after pv frees the single V buffer, consumed next iteration
  int t = warp, buf = 0;
  if (t < nt) {
    v8bf kcur[2][2], knxt[2][2], vprev[4];
    loadK(t, kcur); loadV(t, vprev);
    if (t + AW < nt) loadK(t + AW, knxt);
    qk_exp_store(t, kcur, 0);        // first tile: load exposure unavoidable
    #pragma unroll 2
    for (t += AW; t < nt; t += AW) {
      pv(buf, vprev);                // O += P(t-AW)*V(t-AW); vprev now dead
      loadV(t, vprev);               // V(t) -> consumed next iteration
      #pragma unroll
      for (int f = 0; f < 2; f++)
        #pragma unroll
        for (int g = 0; g < 2; g++) kcur[f][g] = knxt[f][g];
      if (t + AW < nt) loadK(t + AW, knxt);
      qk_exp_store(t, kcur, buf ^ 1);  // K(t) was loaded last iteration
      buf ^= 1;
    }
    pv(buf, vprev);                  // drain: P(t_last)*V(t_last)
  }

  // publish per-wave partials
  #pragma unroll
  for (int ih = 0; ih < 2; ih++) {
    lsum[ih] += __shfl_xor(lsum[ih], 16, 64);
    lsum[ih] += __shfl_xor(lsum[ih], 32, 64);
    #pragma unroll
    for (int oc = 0; oc < 4; oc++)
      #pragma unroll
      for (int r = 0; r < 4; r++)
        shbuf[warp][(oc * 16 + quad * 4 + r) * 33 + ih * 16 + i16] = oacc[ih][oc][r];
  }
  if (lane < 16) {
    shbuf[warp][2112 + lane]      = lsum[0];
    shbuf[warp][2112 + 16 + lane] = lsum[1];
  }
  __syncthreads();

  // merge AW=8 key-split waves; thread (iw, o) handles rows i = iw + 8*rr
  const int o  = tid & 63;
  const int iw = tid >> 6;
  #pragma unroll
  for (int rr = 0; rr < 4; rr++) {
    const int i = iw + rr * 8;
    float L = 0.f, O = 0.f;
    #pragma unroll
    for (int w = 0; w < AW; w++) {
      L += shbuf[w][2112 + i];
      O += shbuf[w][o * 33 + i];
    }
    out[(size_t)(b * TT + i0 + i) * HH + o] = O / L;
  }
}

extern "C" void kernel_launch(void* const* d_in, const int* in_sizes, int n_in,
                              void* d_out, int out_size, void* d_ws, size_t ws_size,
                              hipStream_t stream) {
  const size_t NWP = 3 * 4 * 32 * 64 * 8;      // 196,608 elems wpack
  const size_t NP  = (size_t)BB * TT * HH;     // 4,194,304 elems per pack

  us* wpack = (us*)d_ws;
  us* qpack = wpack + NWP;
  us* kpack = qpack + NP;
  us* vpack = kpack + NP;                      // total ws ~25.5 MB
  float* out = (float*)d_out;

  convertw_kernel<<<96, 256, 0, stream>>>(
      (const float*)d_in[1], (const float*)d_in[2], (const float*)d_in[3], wpack);
  proj_kernel<<<BB * TT / 32, 768, 0, stream>>>(
      (const float*)d_in[0], wpack, qpack, kpack, vpack);
  attn_kernel<<<512, 512, 0, stream>>>(qpack, kpack, vpack, out);
}